// Round 11
// baseline (170.376 us; speedup 1.0000x reference)
//
#include <hip/hip_runtime.h>
#include <hip/hip_bf16.h>

#define DIMC 256
#define STATE 128
#define RANK 64
#define NBATCH 16
#define LSEQ 4096
#define NROWS (NBATCH*LSEQ)   // 65536
#define LN_EPS 1e-5f
#define XSTR 264              // LDS row stride (bf16 elems) for staged x tiles in gemm_inB
#define X1STR 136             // LDS row stride for x1 transpose tile

typedef __attribute__((ext_vector_type(8))) short frag8;   // 8 bf16 (4 VGPRs)
typedef __attribute__((ext_vector_type(4))) float f32x4;   // 4 fp32

union Pack4 { __hip_bfloat16 h[4]; uint2 u; };
union Pack8 { __hip_bfloat16 h[8]; uint4 u; };

__device__ inline void gload_lds16(const void* g, void* l) {
    __builtin_amdgcn_global_load_lds((const __attribute__((address_space(1))) void*)g,
                                     (__attribute__((address_space(3))) void*)l, 16, 0, 0);
}

// Stage a [NROWSW][32-k] bf16 weight slice into LDS linear [row][64B] via global_load_lds.
// Global source pre-swizzled (col ^= (row>>1)&3) so b128 frag reads spread banks.
template<int NROWSW, int NTHR>
__device__ inline void stage_wslice(const __hip_bfloat16* __restrict__ W, int Krow, int k0,
                                    __hip_bfloat16* dst, int t) {
    constexpr int ROUNDS = (NROWSW*64) / (NTHR*16);
    const int lane = t & 63, w = t >> 6;
    #pragma unroll
    for (int j = 0; j < ROUNDS; ++j) {
        int base = (w*ROUNDS + j) << 10;       // wave-uniform byte base in slice
        int X = base + lane*16;
        int r = X >> 6;
        int cg = (X >> 4) & 3;
        const __hip_bfloat16* src = W + (size_t)r*Krow + k0 + ((cg ^ ((r>>1)&3)) << 3);
        gload_lds16(src, (char*)dst + base);
    }
}
__device__ inline frag8 ld_wfrag(const __hip_bfloat16* buf, int row, int q) {
    return *(const frag8*)((const char*)buf + (row<<6) + ((q ^ ((row>>1)&3))<<4));
}

// ---------------- At[j][i] = A[i][j] = sum_r V[i,r]*U[j,r], stored bf16 ----------------
__global__ __launch_bounds__(128) void a_kernel(const float* __restrict__ U, const float* __restrict__ V,
                                                __hip_bfloat16* __restrict__ At) {
    int i = blockIdx.x, j = threadIdx.x;
    float s = 0.f;
    #pragma unroll
    for (int r = 0; r < RANK; ++r) s += V[i*RANK + r] * U[j*RANK + r];
    At[j*STATE + i] = __float2bfloat16(s);
}

// ---------------- weights fp32 -> bf16 ----------------
__global__ __launch_bounds__(256) void prep_weights(const float* __restrict__ in_w, const float* __restrict__ B_w,
                                                    const float* __restrict__ gate_w, const float* __restrict__ out_w,
                                                    __hip_bfloat16* __restrict__ in_wb, __hip_bfloat16* __restrict__ B_wb,
                                                    __hip_bfloat16* __restrict__ gate_wb, __hip_bfloat16* __restrict__ out_wb) {
    int idx = blockIdx.x*256 + threadIdx.x;
    int which = blockIdx.y;
    if (which == 0) { if (idx < STATE*DIMC)  in_wb[idx]   = __float2bfloat16(in_w[idx]); }
    else if (which == 1) { if (idx < STATE*STATE) B_wb[idx] = __float2bfloat16(B_w[idx]); }
    else if (which == 2) { if (idx < DIMC*DIMC)  gate_wb[idx] = __float2bfloat16(gate_w[idx]); }
    else { if (idx < DIMC*STATE) out_wb[idx] = __float2bfloat16(out_w[idx]); }
}

// ---- stage x[b][0..255][l0..l0+64) into LDS bf16 [l][cin^((l&7)<<3)], stride XSTR ----
// (row&7) swizzle: spreads stride-256 frag reads (x_bt path) over all 32 banks.
template<int NTHR>
__device__ inline void stage_x64(const float* __restrict__ xb, int l0,
                                 __hip_bfloat16* __restrict__ xs, int t) {
    constexpr int UN = 1024 / NTHR;
    #pragma unroll
    for (int uu = 0; uu < UN; ++uu) {
        int unit = t + uu*NTHR;
        int lg = unit & 15, cg = unit >> 4;    // cg 0..63, lg 0..15
        int l = lg*4;
        float4 v0 = *(const float4*)(xb + (size_t)(cg*4+0)*LSEQ + l0 + l);
        float4 v1 = *(const float4*)(xb + (size_t)(cg*4+1)*LSEQ + l0 + l);
        float4 v2 = *(const float4*)(xb + (size_t)(cg*4+2)*LSEQ + l0 + l);
        float4 v3 = *(const float4*)(xb + (size_t)(cg*4+3)*LSEQ + l0 + l);
        const float* p0 = (const float*)&v0; const float* p1 = (const float*)&v1;
        const float* p2 = (const float*)&v2; const float* p3 = (const float*)&v3;
        #pragma unroll
        for (int li = 0; li < 4; ++li) {
            Pack4 p;
            p.h[0] = __float2bfloat16(p0[li]);
            p.h[1] = __float2bfloat16(p1[li]);
            p.h[2] = __float2bfloat16(p2[li]);
            p.h[3] = __float2bfloat16(p3[li]);
            int row = l + li;
            int col = (cg*4) ^ ((row&7)<<3);
            *(uint2*)(xs + (size_t)row*XSTR + col) = p.u;
        }
    }
}
__device__ inline frag8 ld_xfrag(const __hip_bfloat16* __restrict__ xs, int row, int k) {
    return *(const frag8*)(xs + (size_t)row*XSTR + (k ^ ((row&7)<<3)));
}
// same content staged linearly at stride DIMC (fused_out path)
__device__ inline frag8 ld_xfrag2(const __hip_bfloat16* __restrict__ xs, int row, int k) {
    return *(const frag8*)(xs + (size_t)row*DIMC + (k ^ ((row&7)<<3)));
}

// ---------------- fused in_proj + B GEMM (r7 __syncthreads pipeline) + x_bt export ----------------
// block = 64 l rows, 512 threads = 8 waves in 4(M) x 2(N).
__global__ __launch_bounds__(512) void gemm_inB(const float* __restrict__ x,
                                                const __hip_bfloat16* __restrict__ in_wb, const float* __restrict__ in_b,
                                                const __hip_bfloat16* __restrict__ B_wb, const float* __restrict__ B_b,
                                                float* __restrict__ state_out, __hip_bfloat16* __restrict__ bxb,
                                                __hip_bfloat16* __restrict__ x_bt) {
    __shared__ __hip_bfloat16 xs[64*XSTR];                  // 33792 B; x1s aliases after GEMM1
    __shared__ __hip_bfloat16 wsl[2][4096];                 // 2 x 8192 B weight slices (128 rows)
    __hip_bfloat16* x1s = xs;
    const int t = threadIdx.x;
    const int lane = t & 63;
    const int c = lane & 15, q = lane >> 4;
    const int w = t >> 6, wm = w >> 1, wc = w & 1;
    const int r0 = blockIdx.x * 64;
    const int b = r0 >> 12, l0 = r0 & 4095;

    stage_x64<512>(x + (size_t)b*DIMC*LSEQ, l0, xs, t);
    stage_wslice<STATE,512>(in_wb, DIMC, 0, wsl[0], t);
    __syncthreads();   // xs writes + slice0 landed

    // export swizzled bf16 x-tile verbatim (rows are 512B of payload; coalesced stores)
    {
        int row = t >> 3, sub = t & 7;
        const char* srcb = (const char*)xs + (size_t)row*(XSTR*2) + sub*64;
        __hip_bfloat16* dstp = x_bt + (size_t)(r0 + row)*DIMC + sub*32;
        #pragma unroll
        for (int j = 0; j < 4; ++j)
            *(uint4*)(dstp + j*8) = *(const uint4*)(srcb + j*16);
    }

    // GEMM 1: x1[l][s] = sum_c x*W_in  (8 k-slices, dbuf, stage-ahead + __syncthreads)
    f32x4 acc[4] = {};
    #pragma unroll
    for (int i = 0; i < 8; ++i) {
        if (i < 7) stage_wslice<STATE,512>(in_wb, DIMC, (i+1)*32, wsl[(i+1)&1], t);
        frag8 af = ld_xfrag(xs, wm*16 + c, i*32 + q*8);
        #pragma unroll
        for (int nt = 0; nt < 4; ++nt) {
            frag8 bf = ld_wfrag(wsl[i&1], wc*64 + nt*16 + c, q);
            acc[nt] = __builtin_amdgcn_mfma_f32_16x16x32_bf16(af, bf, acc[nt], 0, 0, 0);
        }
        __syncthreads();
    }

    stage_wslice<STATE,512>(B_wb, STATE, 0, wsl[0], t);   // prologue for GEMM2 (wsl[0] free)

    // emit x1: fp32 -> state_out, bf16 -> swizzled LDS transpose (x1s keeps row&3 swizzle)
    #pragma unroll
    for (int nt = 0; nt < 4; ++nt) {
        int col = wc*64 + nt*16 + c;
        float bb = in_b[col];
        #pragma unroll
        for (int r = 0; r < 4; ++r) {
            int row = wm*16 + q*4 + r;
            float v = acc[nt][r] + bb;
            state_out[(size_t)(r0 + row)*STATE + col] = v;
            x1s[(size_t)row*X1STR + (col ^ ((row&3)<<3))] = __float2bfloat16(v);
        }
    }
    __syncthreads();

    // GEMM 2: bx[l][s'] = sum_s x1*B_w  (4 k-slices, dbuf)
    f32x4 acc2[4] = {};
    #pragma unroll
    for (int i = 0; i < 4; ++i) {
        if (i < 3) stage_wslice<STATE,512>(B_wb, STATE, (i+1)*32, wsl[(i+1)&1], t);
        int row = wm*16 + c;
        frag8 af = *(const frag8*)(x1s + (size_t)row*X1STR + (((i*32) + q*8) ^ ((row&3)<<3)));
        #pragma unroll
        for (int nt = 0; nt < 4; ++nt) {
            frag8 bf = ld_wfrag(wsl[i&1], wc*64 + nt*16 + c, q);
            acc2[nt] = __builtin_amdgcn_mfma_f32_16x16x32_bf16(af, bf, acc2[nt], 0, 0, 0);
        }
        __syncthreads();
    }
    const int orow = r0 + wm*16 + q*4;
    #pragma unroll
    for (int nt = 0; nt < 4; ++nt) {
        int col = wc*64 + nt*16 + c;
        float bb = B_b[col];
        #pragma unroll
        for (int r = 0; r < 4; ++r)
            bxb[(size_t)(orow + r)*STATE + col] = __float2bfloat16(acc2[nt][r] + bb);
    }
}

// ---------------- MFMA batched scan: 16 scans/block, 4 waves; bx bf16 in, y bf16 out ----------------
#define HSTRIDE 144
__global__ __launch_bounds__(256, 1) void scan_mfma(const __hip_bfloat16* __restrict__ bxb,
                                                    const __hip_bfloat16* __restrict__ At,
                                                    __hip_bfloat16* __restrict__ ylr,
                                                    __hip_bfloat16* __restrict__ yrl) {
    __shared__ __hip_bfloat16 Hb[16 * HSTRIDE];
    const int t = threadIdx.x;
    const int l = t & 63;
    const int wm = t >> 6;
    const int c = l & 15;
    const int q = l >> 4;

    const int S   = blockIdx.x * 16 + c;
    const int dir = S >> 10;
    const int b   = (S >> 6) & 15;
    const int blk = S & 63;
    const int lp0 = blk * 64;
    const int lorig0 = dir ? (LSEQ - 1 - lp0) : lp0;
    const int sgnstep = dir ? -STATE : STATE;

    const __hip_bfloat16* bxrow = bxb + ((size_t)b*LSEQ + lorig0)*STATE;
    __hip_bfloat16* yrow = (dir ? yrl : ylr) + ((size_t)b*LSEQ + lp0)*STATE;

    frag8 afr[2][4];
    #pragma unroll
    for (int mm = 0; mm < 2; ++mm)
        #pragma unroll
        for (int kc = 0; kc < 4; ++kc)
            afr[mm][kc] = *(const frag8*)(At + (size_t)((wm*2+mm)*16 + c)*STATE + kc*32 + q*8);

    for (int k = t; k < 16*HSTRIDE; k += 256) Hb[k] = __float2bfloat16(0.f);
    __syncthreads();

    uint2 pf[2];
    #pragma unroll
    for (int mm = 0; mm < 2; ++mm)
        pf[mm] = *(const uint2*)(bxrow + (wm*2+mm)*16 + q*4);

    for (int tt = 0; tt < 64; ++tt) {
        frag8 bfr[4];
        #pragma unroll
        for (int kc = 0; kc < 4; ++kc)
            bfr[kc] = *(const frag8*)(&Hb[c*HSTRIDE + kc*32 + q*8]);

        f32x4 acc[2];
        #pragma unroll
        for (int mm = 0; mm < 2; ++mm) {
            f32x4 a = {0.f, 0.f, 0.f, 0.f};
            #pragma unroll
            for (int kc = 0; kc < 4; ++kc)
                a = __builtin_amdgcn_mfma_f32_16x16x32_bf16(afr[mm][kc], bfr[kc], a, 0, 0, 0);
            Pack4 pp; pp.u = pf[mm];
            acc[mm][0] = a[0] + __bfloat162float(pp.h[0]);
            acc[mm][1] = a[1] + __bfloat162float(pp.h[1]);
            acc[mm][2] = a[2] + __bfloat162float(pp.h[2]);
            acc[mm][3] = a[3] + __bfloat162float(pp.h[3]);
        }
        if (tt < 63) {
            bxrow += sgnstep;
            #pragma unroll
            for (int mm = 0; mm < 2; ++mm)
                pf[mm] = *(const uint2*)(bxrow + (wm*2+mm)*16 + q*4);
        }

        Pack4 pk[2];
        #pragma unroll
        for (int mm = 0; mm < 2; ++mm) {
            pk[mm].h[0] = __float2bfloat16(acc[mm][0]);
            pk[mm].h[1] = __float2bfloat16(acc[mm][1]);
            pk[mm].h[2] = __float2bfloat16(acc[mm][2]);
            pk[mm].h[3] = __float2bfloat16(acc[mm][3]);
        }
        #pragma unroll
        for (int mm = 0; mm < 2; ++mm)
            *(uint2*)(yrow + (wm*2+mm)*16 + q*4) = pk[mm].u;
        yrow += STATE;

        __syncthreads();
        #pragma unroll
        for (int mm = 0; mm < 2; ++mm)
            *(uint2*)(&Hb[c*HSTRIDE + (wm*2+mm)*16 + q*4]) = pk[mm].u;
        __syncthreads();
    }
}

// ---------------- conv7 + combine: u = 0.5*(conv(ylr)+rev(conv(yrl))) + conv_b, bf16 io ----------------
__global__ __launch_bounds__(128) void conv_combine(const __hip_bfloat16* __restrict__ ylr,
                                                    const __hip_bfloat16* __restrict__ yrl,
                                                    const float* __restrict__ conv_w, const float* __restrict__ conv_b,
                                                    __hip_bfloat16* __restrict__ u) {
    const int t = threadIdx.x;
    const int s8 = (t & 15) * 8;
    const int l = blockIdx.x * 8 + (t >> 4);
    const int b = blockIdx.y;

    float wv[8][7];
    #pragma unroll
    for (int j = 0; j < 8; ++j)
        #pragma unroll
        for (int i = 0; i < 7; ++i) wv[j][i] = conv_w[(s8+j)*7 + i];

    const __hip_bfloat16* plr = ylr + (size_t)b*LSEQ*STATE;
    const __hip_bfloat16* prl = yrl + (size_t)b*LSEQ*STATE;

    float acc[8];
    {
        Pack8 v; v.u = *(const uint4*)(plr + (size_t)l*STATE + s8);
        #pragma unroll
        for (int j = 0; j < 8; ++j) acc[j] = __bfloat162float(v.h[j]);
    }
    #pragma unroll
    for (int i = 0; i < 7; ++i) {
        int qq = l - 3 + i;
        if (qq >= 0 && qq < LSEQ) {
            Pack8 v; v.u = *(const uint4*)(plr + (size_t)qq*STATE + s8);
            #pragma unroll
            for (int j = 0; j < 8; ++j) acc[j] += wv[j][i] * __bfloat162float(v.h[j]);
        }
    }
    const int lp = LSEQ - 1 - l;
    {
        Pack8 v; v.u = *(const uint4*)(prl + (size_t)lp*STATE + s8);
        #pragma unroll
        for (int j = 0; j < 8; ++j) acc[j] += __bfloat162float(v.h[j]);
    }
    #pragma unroll
    for (int i = 0; i < 7; ++i) {
        int qq = lp - 3 + i;
        if (qq >= 0 && qq < LSEQ) {
            Pack8 v; v.u = *(const uint4*)(prl + (size_t)qq*STATE + s8);
            #pragma unroll
            for (int j = 0; j < 8; ++j) acc[j] += wv[j][i] * __bfloat162float(v.h[j]);
        }
    }
    Pack8 o;
    #pragma unroll
    for (int j = 0; j < 8; ++j) o.h[j] = __float2bfloat16(0.5f*acc[j] + conv_b[s8+j]);
    *(uint4*)(u + ((size_t)b*LSEQ + l)*STATE + s8) = o.u;
}

// ---------------- fused MFMA: gate+out GEMM (r7 pipeline) + epilogue; A from x_bt via DMA ----------------
// block = 64 l x 256 c; 512 threads = 8 waves in 4(M) x 2(N).
__global__ __launch_bounds__(512) void fused_out(const __hip_bfloat16* __restrict__ x_bt,
    const __hip_bfloat16* __restrict__ ub,
    const __hip_bfloat16* __restrict__ out_wb, const float* __restrict__ out_b,
    const __hip_bfloat16* __restrict__ gate_wb, const float* __restrict__ gate_b,
    const float* __restrict__ norm_g, const float* __restrict__ norm_b,
    float* __restrict__ y) {
    __shared__ __hip_bfloat16 xs2[64*DIMC];        // 32768 B, linear, content pre-swizzled
    __shared__ __hip_bfloat16 wsl[2][8192];        // 2 x 16384 B weight slices (256 rows)
    __shared__ float lnbuf[4][2][16][2];
    const int t = threadIdx.x;
    const int lane = t & 63, c = lane & 15, q = lane >> 4;
    const int w = t >> 6, wm = w >> 1, wc = w & 1;
    const int r0 = blockIdx.x * 64;
    const int b = r0 >> 12, l0 = r0 & 4095;

    // stage x tile: pure DMA (4 x global_load_lds per thread, zero VALU)
    {
        const char* srcx = (const char*)(x_bt + (size_t)r0*DIMC);
        #pragma unroll
        for (int j = 0; j < 4; ++j) {
            int base = (w*256 + j*64) * 16;        // wave-uniform byte base
            gload_lds16(srcx + base + lane*16, (char*)xs2 + base);
        }
    }
    // u A-frags prefetched to registers (drained by the prologue __syncthreads)
    frag8 ufr[4];
    {
        const int arow = r0 + wm*16 + c;
        #pragma unroll
        for (int kc = 0; kc < 4; ++kc)
            ufr[kc] = *(const frag8*)(ub + (size_t)arow*STATE + kc*32 + q*8);
    }
    stage_wslice<DIMC,512>(gate_wb, DIMC, 0, wsl[0], t);
    __syncthreads();   // xs2 DMA + ufr + slice0 landed

    f32x4 accg[8] = {};
    f32x4 acco[8] = {};
    #pragma unroll
    for (int i = 0; i < 12; ++i) {
        if (i < 11) {
            if (i < 7) stage_wslice<DIMC,512>(gate_wb, DIMC, (i+1)*32, wsl[(i+1)&1], t);
            else       stage_wslice<DIMC,512>(out_wb,  STATE, (i-7)*32, wsl[(i+1)&1], t);
        }
        if (i < 8) {
            frag8 af = ld_xfrag2(xs2, wm*16 + c, i*32 + q*8);
            #pragma unroll
            for (int nt = 0; nt < 8; ++nt) {
                frag8 bf = ld_wfrag(wsl[i&1], wc*128 + nt*16 + c, q);
                accg[nt] = __builtin_amdgcn_mfma_f32_16x16x32_bf16(af, bf, accg[nt], 0, 0, 0);
            }
        } else {
            frag8 af = ufr[i-8];
            #pragma unroll
            for (int nt = 0; nt < 8; ++nt) {
                frag8 bf = ld_wfrag(wsl[i&1], wc*128 + nt*16 + c, q);
                acco[nt] = __builtin_amdgcn_mfma_f32_16x16x32_bf16(af, bf, acco[nt], 0, 0, 0);
            }
        }
        __syncthreads();
    }

    // epilogue in registers: v = sigmoid(gate)*o + residual(from xs2); LN partials
    float s1[4] = {0.f,0.f,0.f,0.f}, s2[4] = {0.f,0.f,0.f,0.f};
    #pragma unroll
    for (int nt = 0; nt < 8; ++nt) {
        int col = wc*128 + nt*16 + c;
        float gb = gate_b[col], ob = out_b[col];
        #pragma unroll
        for (int r = 0; r < 4; ++r) {
            int row = wm*16 + q*4 + r;
            float res = __bfloat162float(xs2[(size_t)row*DIMC + (col ^ ((row&7)<<3))]);
            float g = 1.f/(1.f + expf(-(accg[nt][r] + gb)));
            float v = g*(acco[nt][r] + ob) + res;
            accg[nt][r] = v;
            s1[r] += v; s2[r] += v*v;
        }
    }
    #pragma unroll
    for (int m = 1; m <= 8; m <<= 1) {
        #pragma unroll
        for (int r = 0; r < 4; ++r) {
            s1[r] += __shfl_xor(s1[r], m);
            s2[r] += __shfl_xor(s2[r], m);
        }
    }
    if (c == 0) {
        #pragma unroll
        for (int r = 0; r < 4; ++r) {
            lnbuf[wm][wc][q*4 + r][0] = s1[r];
            lnbuf[wm][wc][q*4 + r][1] = s2[r];
        }
    }
    __syncthreads();
    float mu[4], rstd[4];
    #pragma unroll
    for (int r = 0; r < 4; ++r) {
        int row16 = q*4 + r;
        float t1 = lnbuf[wm][0][row16][0] + lnbuf[wm][1][row16][0];
        float t2 = lnbuf[wm][0][row16][1] + lnbuf[wm][1][row16][1];
        float m_ = t1 * (1.f/256.f);
        mu[r] = m_;
        rstd[r] = rsqrtf(t2 * (1.f/256.f) - m_*m_ + LN_EPS);
    }
    #pragma unroll
    for (int nt = 0; nt < 8; ++nt) {
        int col = wc*128 + nt*16 + c;
        float g = norm_g[col], be = norm_b[col];
        float4 v4;
        v4.x = (accg[nt][0] - mu[0]) * rstd[0] * g + be;
        v4.y = (accg[nt][1] - mu[1]) * rstd[1] * g + be;
        v4.z = (accg[nt][2] - mu[2]) * rstd[2] * g + be;
        v4.w = (accg[nt][3] - mu[3]) * rstd[3] * g + be;
        *(float4*)(y + ((size_t)b*DIMC + col)*LSEQ + l0 + wm*16 + q*4) = v4;
    }
}

extern "C" void kernel_launch(void* const* d_in, const int* in_sizes, int n_in,
                              void* d_out, int out_size, void* d_ws, size_t ws_size,
                              hipStream_t stream) {
    const float* x      = (const float*)d_in[0];
    const float* in_w   = (const float*)d_in[1];
    const float* in_b   = (const float*)d_in[2];
    const float* U      = (const float*)d_in[3];
    const float* V      = (const float*)d_in[4];
    const float* B_w    = (const float*)d_in[5];
    const float* B_b    = (const float*)d_in[6];
    const float* out_w  = (const float*)d_in[7];
    const float* out_b  = (const float*)d_in[8];
    const float* gate_w = (const float*)d_in[9];
    const float* gate_b = (const float*)d_in[10];
    const float* norm_g = (const float*)d_in[11];
    const float* norm_b = (const float*)d_in[12];
    const float* conv_w = (const float*)d_in[13];
    const float* conv_b = (const float*)d_in[14];

    float* yfinal = (float*)d_out;                                 // [16][256][64][64]
    float* state_out = yfinal + (size_t)NBATCH*DIMC*LSEQ;          // [16][4096][128] fp32

    float* ws  = (float*)d_ws;
    __hip_bfloat16* bxb = (__hip_bfloat16*)ws;                     // bx bf16; later u bf16 (aliased)
    __hip_bfloat16* ub  = (__hip_bfloat16*)ws;
    __hip_bfloat16* Atb16  = (__hip_bfloat16*)(ws + (size_t)NROWS*STATE);
    __hip_bfloat16* in_wb  = Atb16 + STATE*STATE;
    __hip_bfloat16* B_wb   = in_wb + STATE*DIMC;
    __hip_bfloat16* gate_wb= B_wb + STATE*STATE;
    __hip_bfloat16* out_wb = gate_wb + DIMC*DIMC;
    __hip_bfloat16* x_bt   = out_wb + DIMC*STATE;                  // [NROWS][DIMC] bf16, swizzled rows

    // bf16 scan outputs live in the (later overwritten) y region of d_out
    __hip_bfloat16* ylr = (__hip_bfloat16*)yfinal;                 // NROWS*STATE bf16
    __hip_bfloat16* yrl = ylr + (size_t)NROWS*STATE;               // NROWS*STATE bf16

    a_kernel<<<dim3(STATE), dim3(STATE), 0, stream>>>(U, V, Atb16);
    prep_weights<<<dim3(256, 4), dim3(256), 0, stream>>>(in_w, B_w, gate_w, out_w,
                                                         in_wb, B_wb, gate_wb, out_wb);
    gemm_inB<<<dim3(NROWS/64), dim3(512), 0, stream>>>(x, in_wb, in_b, B_wb, B_b,
                                                       state_out, bxb, x_bt);
    scan_mfma<<<dim3(128), dim3(256), 0, stream>>>(bxb, Atb16, ylr, yrl);
    conv_combine<<<dim3(LSEQ/8, NBATCH), dim3(128), 0, stream>>>(ylr, yrl, conv_w, conv_b, ub);
    fused_out<<<dim3(NROWS/64), dim3(512), 0, stream>>>(x_bt, ub, out_wb, out_b, gate_wb, gate_b,
                                                        norm_g, norm_b, yfinal);
    (void)in_sizes; (void)n_in; (void)out_size; (void)ws_size;
}

// Round 12
// 167.753 us; speedup vs baseline: 1.0156x; 1.0156x over previous
//
#include <hip/hip_runtime.h>
#include <hip/hip_bf16.h>

#define DIMC 256
#define STATE 128
#define RANK 64
#define NBATCH 16
#define LSEQ 4096
#define NROWS (NBATCH*LSEQ)   // 65536
#define LN_EPS 1e-5f
#define XSTR 264              // LDS row stride (bf16 elems) for staged x tiles
#define X1STR 136             // LDS row stride for x1 transpose tile

typedef __attribute__((ext_vector_type(8))) short frag8;   // 8 bf16 (4 VGPRs)
typedef __attribute__((ext_vector_type(4))) float f32x4;   // 4 fp32

union Pack4 { __hip_bfloat16 h[4]; uint2 u; };
union Pack8 { __hip_bfloat16 h[8]; uint4 u; };

__device__ inline void gload_lds16(const void* g, void* l) {
    __builtin_amdgcn_global_load_lds((const __attribute__((address_space(1))) void*)g,
                                     (__attribute__((address_space(3))) void*)l, 16, 0, 0);
}

// Stage a [NROWSW][32-k] bf16 weight slice into LDS linear [row][64B] via global_load_lds.
// Global source pre-swizzled (col ^= (row>>1)&3) so b128 frag reads spread banks.
template<int NROWSW, int NTHR>
__device__ inline void stage_wslice(const __hip_bfloat16* __restrict__ W, int Krow, int k0,
                                    __hip_bfloat16* dst, int t) {
    constexpr int ROUNDS = (NROWSW*64) / (NTHR*16);
    const int lane = t & 63, w = t >> 6;
    #pragma unroll
    for (int j = 0; j < ROUNDS; ++j) {
        int base = (w*ROUNDS + j) << 10;       // wave-uniform byte base in slice
        int X = base + lane*16;
        int r = X >> 6;
        int cg = (X >> 4) & 3;
        const __hip_bfloat16* src = W + (size_t)r*Krow + k0 + ((cg ^ ((r>>1)&3)) << 3);
        gload_lds16(src, (char*)dst + base);
    }
}
__device__ inline frag8 ld_wfrag(const __hip_bfloat16* buf, int row, int q) {
    return *(const frag8*)((const char*)buf + (row<<6) + ((q ^ ((row>>1)&3))<<4));
}

// ---------------- At[j][i] = A[i][j] = sum_r V[i,r]*U[j,r], stored bf16 ----------------
__global__ __launch_bounds__(128) void a_kernel(const float* __restrict__ U, const float* __restrict__ V,
                                                __hip_bfloat16* __restrict__ At) {
    int i = blockIdx.x, j = threadIdx.x;
    float s = 0.f;
    #pragma unroll
    for (int r = 0; r < RANK; ++r) s += V[i*RANK + r] * U[j*RANK + r];
    At[j*STATE + i] = __float2bfloat16(s);
}

// ---------------- weights fp32 -> bf16 ----------------
__global__ __launch_bounds__(256) void prep_weights(const float* __restrict__ in_w, const float* __restrict__ B_w,
                                                    const float* __restrict__ gate_w, const float* __restrict__ out_w,
                                                    __hip_bfloat16* __restrict__ in_wb, __hip_bfloat16* __restrict__ B_wb,
                                                    __hip_bfloat16* __restrict__ gate_wb, __hip_bfloat16* __restrict__ out_wb) {
    int idx = blockIdx.x*256 + threadIdx.x;
    int which = blockIdx.y;
    if (which == 0) { if (idx < STATE*DIMC)  in_wb[idx]   = __float2bfloat16(in_w[idx]); }
    else if (which == 1) { if (idx < STATE*STATE) B_wb[idx] = __float2bfloat16(B_w[idx]); }
    else if (which == 2) { if (idx < DIMC*DIMC)  gate_wb[idx] = __float2bfloat16(gate_w[idx]); }
    else { if (idx < DIMC*STATE) out_wb[idx] = __float2bfloat16(out_w[idx]); }
}

// ---- stage x[b][0..255][l0..l0+64) into LDS bf16 [l][cin^((l&3)<<3)], stride XSTR ----
// 1024 units of (4ch x 4l); per unit: 4x float4 coalesced loads -> in-reg transpose -> 4x ds_write_b64
template<int NTHR>
__device__ inline void stage_x64(const float* __restrict__ xb, int l0,
                                 __hip_bfloat16* __restrict__ xs, int t) {
    constexpr int UN = 1024 / NTHR;
    #pragma unroll
    for (int uu = 0; uu < UN; ++uu) {
        int unit = t + uu*NTHR;
        int lg = unit & 15, cg = unit >> 4;    // cg 0..63, lg 0..15
        int l = lg*4;
        float4 v0 = *(const float4*)(xb + (size_t)(cg*4+0)*LSEQ + l0 + l);
        float4 v1 = *(const float4*)(xb + (size_t)(cg*4+1)*LSEQ + l0 + l);
        float4 v2 = *(const float4*)(xb + (size_t)(cg*4+2)*LSEQ + l0 + l);
        float4 v3 = *(const float4*)(xb + (size_t)(cg*4+3)*LSEQ + l0 + l);
        const float* p0 = (const float*)&v0; const float* p1 = (const float*)&v1;
        const float* p2 = (const float*)&v2; const float* p3 = (const float*)&v3;
        #pragma unroll
        for (int li = 0; li < 4; ++li) {
            Pack4 p;
            p.h[0] = __float2bfloat16(p0[li]);
            p.h[1] = __float2bfloat16(p1[li]);
            p.h[2] = __float2bfloat16(p2[li]);
            p.h[3] = __float2bfloat16(p3[li]);
            int row = l + li;
            int col = (cg*4) ^ ((row&3)<<3);
            *(uint2*)(xs + (size_t)row*XSTR + col) = p.u;
        }
    }
}
__device__ inline frag8 ld_xfrag(const __hip_bfloat16* __restrict__ xs, int row, int k) {
    return *(const frag8*)(xs + (size_t)row*XSTR + (k ^ ((row&3)<<3)));
}

// ---------------- fused in_proj + B GEMM with LDS-staged dbuf weights; bx out bf16 ----------------
// block = 64 l rows, 512 threads = 8 waves in 4(M) x 2(N). Proven r7 __syncthreads pipeline.
__global__ __launch_bounds__(512) void gemm_inB(const float* __restrict__ x,
                                                const __hip_bfloat16* __restrict__ in_wb, const float* __restrict__ in_b,
                                                const __hip_bfloat16* __restrict__ B_wb, const float* __restrict__ B_b,
                                                float* __restrict__ state_out, __hip_bfloat16* __restrict__ bxb) {
    __shared__ __hip_bfloat16 xs[64*XSTR];                  // 33792 B; x1s aliases after GEMM1
    __shared__ __hip_bfloat16 wsl[2][4096];                 // 2 x 8192 B weight slices
    __hip_bfloat16* x1s = xs;
    const int t = threadIdx.x;
    const int lane = t & 63;
    const int c = lane & 15, q = lane >> 4;
    const int w = t >> 6, wm = w >> 1, wc = w & 1;
    const int r0 = blockIdx.x * 64;
    const int b = r0 >> 12, l0 = r0 & 4095;

    stage_x64<512>(x + (size_t)b*DIMC*LSEQ, l0, xs, t);
    stage_wslice<STATE,512>(in_wb, DIMC, 0, wsl[0], t);
    __syncthreads();

    // GEMM 1: x1[l][s] = sum_c x*W_in  (8 k-slices, dbuf)
    f32x4 acc[4] = {};
    #pragma unroll
    for (int i = 0; i < 8; ++i) {
        if (i < 7) stage_wslice<STATE,512>(in_wb, DIMC, (i+1)*32, wsl[(i+1)&1], t);
        frag8 af = ld_xfrag(xs, wm*16 + c, i*32 + q*8);
        #pragma unroll
        for (int nt = 0; nt < 4; ++nt) {
            frag8 bf = ld_wfrag(wsl[i&1], wc*64 + nt*16 + c, q);
            acc[nt] = __builtin_amdgcn_mfma_f32_16x16x32_bf16(af, bf, acc[nt], 0, 0, 0);
        }
        __syncthreads();
    }

    stage_wslice<STATE,512>(B_wb, STATE, 0, wsl[0], t);   // prologue for GEMM2

    // emit x1: fp32 -> state_out, bf16 -> swizzled LDS transpose
    #pragma unroll
    for (int nt = 0; nt < 4; ++nt) {
        int col = wc*64 + nt*16 + c;
        float bb = in_b[col];
        #pragma unroll
        for (int r = 0; r < 4; ++r) {
            int row = wm*16 + q*4 + r;
            float v = acc[nt][r] + bb;
            state_out[(size_t)(r0 + row)*STATE + col] = v;
            x1s[(size_t)row*X1STR + (col ^ ((row&3)<<3))] = __float2bfloat16(v);
        }
    }
    __syncthreads();

    // GEMM 2: bx[l][s'] = sum_s x1*B_w  (4 k-slices, dbuf)
    f32x4 acc2[4] = {};
    #pragma unroll
    for (int i = 0; i < 4; ++i) {
        if (i < 3) stage_wslice<STATE,512>(B_wb, STATE, (i+1)*32, wsl[(i+1)&1], t);
        int row = wm*16 + c;
        frag8 af = *(const frag8*)(x1s + (size_t)row*X1STR + (((i*32) + q*8) ^ ((row&3)<<3)));
        #pragma unroll
        for (int nt = 0; nt < 4; ++nt) {
            frag8 bf = ld_wfrag(wsl[i&1], wc*64 + nt*16 + c, q);
            acc2[nt] = __builtin_amdgcn_mfma_f32_16x16x32_bf16(af, bf, acc2[nt], 0, 0, 0);
        }
        __syncthreads();
    }
    const int orow = r0 + wm*16 + q*4;
    #pragma unroll
    for (int nt = 0; nt < 4; ++nt) {
        int col = wc*64 + nt*16 + c;
        float bb = B_b[col];
        #pragma unroll
        for (int r = 0; r < 4; ++r)
            bxb[(size_t)(orow + r)*STATE + col] = __float2bfloat16(acc2[nt][r] + bb);
    }
}

// ---------------- MFMA batched scan: 16 scans/block, 4 waves; bx bf16 in, y bf16 out ----------------
#define HSTRIDE 144
__global__ __launch_bounds__(256, 1) void scan_mfma(const __hip_bfloat16* __restrict__ bxb,
                                                    const __hip_bfloat16* __restrict__ At,
                                                    __hip_bfloat16* __restrict__ ylr,
                                                    __hip_bfloat16* __restrict__ yrl) {
    __shared__ __hip_bfloat16 Hb[16 * HSTRIDE];
    const int t = threadIdx.x;
    const int l = t & 63;
    const int wm = t >> 6;
    const int c = l & 15;
    const int q = l >> 4;

    const int S   = blockIdx.x * 16 + c;
    const int dir = S >> 10;
    const int b   = (S >> 6) & 15;
    const int blk = S & 63;
    const int lp0 = blk * 64;
    const int lorig0 = dir ? (LSEQ - 1 - lp0) : lp0;
    const int sgnstep = dir ? -STATE : STATE;

    const __hip_bfloat16* bxrow = bxb + ((size_t)b*LSEQ + lorig0)*STATE;
    __hip_bfloat16* yrow = (dir ? yrl : ylr) + ((size_t)b*LSEQ + lp0)*STATE;

    frag8 afr[2][4];
    #pragma unroll
    for (int mm = 0; mm < 2; ++mm)
        #pragma unroll
        for (int kc = 0; kc < 4; ++kc)
            afr[mm][kc] = *(const frag8*)(At + (size_t)((wm*2+mm)*16 + c)*STATE + kc*32 + q*8);

    for (int k = t; k < 16*HSTRIDE; k += 256) Hb[k] = __float2bfloat16(0.f);
    __syncthreads();

    uint2 pf[2];
    #pragma unroll
    for (int mm = 0; mm < 2; ++mm)
        pf[mm] = *(const uint2*)(bxrow + (wm*2+mm)*16 + q*4);

    for (int tt = 0; tt < 64; ++tt) {
        frag8 bfr[4];
        #pragma unroll
        for (int kc = 0; kc < 4; ++kc)
            bfr[kc] = *(const frag8*)(&Hb[c*HSTRIDE + kc*32 + q*8]);

        f32x4 acc[2];
        #pragma unroll
        for (int mm = 0; mm < 2; ++mm) {
            f32x4 a = {0.f, 0.f, 0.f, 0.f};
            #pragma unroll
            for (int kc = 0; kc < 4; ++kc)
                a = __builtin_amdgcn_mfma_f32_16x16x32_bf16(afr[mm][kc], bfr[kc], a, 0, 0, 0);
            Pack4 pp; pp.u = pf[mm];
            acc[mm][0] = a[0] + __bfloat162float(pp.h[0]);
            acc[mm][1] = a[1] + __bfloat162float(pp.h[1]);
            acc[mm][2] = a[2] + __bfloat162float(pp.h[2]);
            acc[mm][3] = a[3] + __bfloat162float(pp.h[3]);
        }
        if (tt < 63) {
            bxrow += sgnstep;
            #pragma unroll
            for (int mm = 0; mm < 2; ++mm)
                pf[mm] = *(const uint2*)(bxrow + (wm*2+mm)*16 + q*4);
        }

        Pack4 pk[2];
        #pragma unroll
        for (int mm = 0; mm < 2; ++mm) {
            pk[mm].h[0] = __float2bfloat16(acc[mm][0]);
            pk[mm].h[1] = __float2bfloat16(acc[mm][1]);
            pk[mm].h[2] = __float2bfloat16(acc[mm][2]);
            pk[mm].h[3] = __float2bfloat16(acc[mm][3]);
        }
        #pragma unroll
        for (int mm = 0; mm < 2; ++mm)
            *(uint2*)(yrow + (wm*2+mm)*16 + q*4) = pk[mm].u;
        yrow += STATE;

        __syncthreads();
        #pragma unroll
        for (int mm = 0; mm < 2; ++mm)
            *(uint2*)(&Hb[c*HSTRIDE + (wm*2+mm)*16 + q*4]) = pk[mm].u;
        __syncthreads();
    }
}

// ---------------- conv7 + combine: u = 0.5*(conv(ylr)+rev(conv(yrl))) + conv_b, bf16 io ----------------
__global__ __launch_bounds__(128) void conv_combine(const __hip_bfloat16* __restrict__ ylr,
                                                    const __hip_bfloat16* __restrict__ yrl,
                                                    const float* __restrict__ conv_w, const float* __restrict__ conv_b,
                                                    __hip_bfloat16* __restrict__ u) {
    const int t = threadIdx.x;
    const int s8 = (t & 15) * 8;
    const int l = blockIdx.x * 8 + (t >> 4);
    const int b = blockIdx.y;

    float wv[8][7];
    #pragma unroll
    for (int j = 0; j < 8; ++j)
        #pragma unroll
        for (int i = 0; i < 7; ++i) wv[j][i] = conv_w[(s8+j)*7 + i];

    const __hip_bfloat16* plr = ylr + (size_t)b*LSEQ*STATE;
    const __hip_bfloat16* prl = yrl + (size_t)b*LSEQ*STATE;

    float acc[8];
    {
        Pack8 v; v.u = *(const uint4*)(plr + (size_t)l*STATE + s8);
        #pragma unroll
        for (int j = 0; j < 8; ++j) acc[j] = __bfloat162float(v.h[j]);
    }
    #pragma unroll
    for (int i = 0; i < 7; ++i) {
        int qq = l - 3 + i;
        if (qq >= 0 && qq < LSEQ) {
            Pack8 v; v.u = *(const uint4*)(plr + (size_t)qq*STATE + s8);
            #pragma unroll
            for (int j = 0; j < 8; ++j) acc[j] += wv[j][i] * __bfloat162float(v.h[j]);
        }
    }
    const int lp = LSEQ - 1 - l;
    {
        Pack8 v; v.u = *(const uint4*)(prl + (size_t)lp*STATE + s8);
        #pragma unroll
        for (int j = 0; j < 8; ++j) acc[j] += __bfloat162float(v.h[j]);
    }
    #pragma unroll
    for (int i = 0; i < 7; ++i) {
        int qq = lp - 3 + i;
        if (qq >= 0 && qq < LSEQ) {
            Pack8 v; v.u = *(const uint4*)(prl + (size_t)qq*STATE + s8);
            #pragma unroll
            for (int j = 0; j < 8; ++j) acc[j] += wv[j][i] * __bfloat162float(v.h[j]);
        }
    }
    Pack8 o;
    #pragma unroll
    for (int j = 0; j < 8; ++j) o.h[j] = __float2bfloat16(0.5f*acc[j] + conv_b[s8+j]);
    *(uint4*)(u + ((size_t)b*LSEQ + l)*STATE + s8) = o.u;
}

// ---------------- fused MFMA: gate+out GEMM (LDS-staged dbuf weights) + epilogue ----------------
// block = 64 l x 256 c; 512 threads = 8 waves in 4(M) x 2(N). Proven r7 structure.
__global__ __launch_bounds__(512) void fused_out(const float* __restrict__ x, const __hip_bfloat16* __restrict__ ub,
    const __hip_bfloat16* __restrict__ out_wb, const float* __restrict__ out_b,
    const __hip_bfloat16* __restrict__ gate_wb, const float* __restrict__ gate_b,
    const float* __restrict__ norm_g, const float* __restrict__ norm_b,
    float* __restrict__ y) {
    __shared__ __hip_bfloat16 xs[64*XSTR];         // 33792 B
    __shared__ __hip_bfloat16 wsl[2][8192];        // 2 x 16384 B weight slices (256 rows)
    __shared__ float lnbuf[4][2][16][2];
    const int t = threadIdx.x;
    const int lane = t & 63, c = lane & 15, q = lane >> 4;
    const int w = t >> 6, wm = w >> 1, wc = w & 1;
    const int r0 = blockIdx.x * 64;
    const int b = r0 >> 12, l0 = r0 & 4095;

    stage_x64<512>(x + (size_t)b*DIMC*LSEQ, l0, xs, t);
    // u A-frags prefetched to registers (latency hidden under gate GEMM)
    frag8 ufr[4];
    {
        const int arow = r0 + wm*16 + c;
        #pragma unroll
        for (int kc = 0; kc < 4; ++kc)
            ufr[kc] = *(const frag8*)(ub + (size_t)arow*STATE + kc*32 + q*8);
    }
    stage_wslice<DIMC,512>(gate_wb, DIMC, 0, wsl[0], t);
    __syncthreads();

    f32x4 accg[8] = {};
    f32x4 acco[8] = {};
    #pragma unroll
    for (int i = 0; i < 12; ++i) {
        if (i < 11) {
            if (i < 7) stage_wslice<DIMC,512>(gate_wb, DIMC, (i+1)*32, wsl[(i+1)&1], t);
            else       stage_wslice<DIMC,512>(out_wb,  STATE, (i-7)*32, wsl[(i+1)&1], t);
        }
        if (i < 8) {
            frag8 af = ld_xfrag(xs, wm*16 + c, i*32 + q*8);
            #pragma unroll
            for (int nt = 0; nt < 8; ++nt) {
                frag8 bf = ld_wfrag(wsl[i&1], wc*128 + nt*16 + c, q);
                accg[nt] = __builtin_amdgcn_mfma_f32_16x16x32_bf16(af, bf, accg[nt], 0, 0, 0);
            }
        } else {
            frag8 af = ufr[i-8];
            #pragma unroll
            for (int nt = 0; nt < 8; ++nt) {
                frag8 bf = ld_wfrag(wsl[i&1], wc*128 + nt*16 + c, q);
                acco[nt] = __builtin_amdgcn_mfma_f32_16x16x32_bf16(af, bf, acco[nt], 0, 0, 0);
            }
        }
        __syncthreads();
    }

    // epilogue in registers: v = sigmoid(gate)*o + residual(from xs); LN partials
    float s1[4] = {0.f,0.f,0.f,0.f}, s2[4] = {0.f,0.f,0.f,0.f};
    #pragma unroll
    for (int nt = 0; nt < 8; ++nt) {
        int col = wc*128 + nt*16 + c;
        float gb = gate_b[col], ob = out_b[col];
        #pragma unroll
        for (int r = 0; r < 4; ++r) {
            int row = wm*16 + q*4 + r;
            float res = __bfloat162float(xs[(size_t)row*XSTR + (col ^ ((row&3)<<3))]);
            float g = 1.f/(1.f + expf(-(accg[nt][r] + gb)));
            float v = g*(acco[nt][r] + ob) + res;
            accg[nt][r] = v;
            s1[r] += v; s2[r] += v*v;
        }
    }
    #pragma unroll
    for (int m = 1; m <= 8; m <<= 1) {
        #pragma unroll
        for (int r = 0; r < 4; ++r) {
            s1[r] += __shfl_xor(s1[r], m);
            s2[r] += __shfl_xor(s2[r], m);
        }
    }
    if (c == 0) {
        #pragma unroll
        for (int r = 0; r < 4; ++r) {
            lnbuf[wm][wc][q*4 + r][0] = s1[r];
            lnbuf[wm][wc][q*4 + r][1] = s2[r];
        }
    }
    __syncthreads();
    float mu[4], rstd[4];
    #pragma unroll
    for (int r = 0; r < 4; ++r) {
        int row16 = q*4 + r;
        float t1 = lnbuf[wm][0][row16][0] + lnbuf[wm][1][row16][0];
        float t2 = lnbuf[wm][0][row16][1] + lnbuf[wm][1][row16][1];
        float m_ = t1 * (1.f/256.f);
        mu[r] = m_;
        rstd[r] = rsqrtf(t2 * (1.f/256.f) - m_*m_ + LN_EPS);
    }
    #pragma unroll
    for (int nt = 0; nt < 8; ++nt) {
        int col = wc*128 + nt*16 + c;
        float g = norm_g[col], be = norm_b[col];
        float4 v4;
        v4.x = (accg[nt][0] - mu[0]) * rstd[0] * g + be;
        v4.y = (accg[nt][1] - mu[1]) * rstd[1] * g + be;
        v4.z = (accg[nt][2] - mu[2]) * rstd[2] * g + be;
        v4.w = (accg[nt][3] - mu[3]) * rstd[3] * g + be;
        *(float4*)(y + ((size_t)b*DIMC + col)*LSEQ + l0 + wm*16 + q*4) = v4;
    }
}

extern "C" void kernel_launch(void* const* d_in, const int* in_sizes, int n_in,
                              void* d_out, int out_size, void* d_ws, size_t ws_size,
                              hipStream_t stream) {
    const float* x      = (const float*)d_in[0];
    const float* in_w   = (const float*)d_in[1];
    const float* in_b   = (const float*)d_in[2];
    const float* U      = (const float*)d_in[3];
    const float* V      = (const float*)d_in[4];
    const float* B_w    = (const float*)d_in[5];
    const float* B_b    = (const float*)d_in[6];
    const float* out_w  = (const float*)d_in[7];
    const float* out_b  = (const float*)d_in[8];
    const float* gate_w = (const float*)d_in[9];
    const float* gate_b = (const float*)d_in[10];
    const float* norm_g = (const float*)d_in[11];
    const float* norm_b = (const float*)d_in[12];
    const float* conv_w = (const float*)d_in[13];
    const float* conv_b = (const float*)d_in[14];

    float* yfinal = (float*)d_out;                                 // [16][256][64][64]
    float* state_out = yfinal + (size_t)NBATCH*DIMC*LSEQ;          // [16][4096][128] fp32

    float* ws  = (float*)d_ws;
    __hip_bfloat16* bxb = (__hip_bfloat16*)ws;                     // bx bf16; later u bf16 (aliased)
    __hip_bfloat16* ub  = (__hip_bfloat16*)ws;
    __hip_bfloat16* Atb16  = (__hip_bfloat16*)(ws + (size_t)NROWS*STATE);
    __hip_bfloat16* in_wb  = Atb16 + STATE*STATE;
    __hip_bfloat16* B_wb   = in_wb + STATE*DIMC;
    __hip_bfloat16* gate_wb= B_wb + STATE*STATE;
    __hip_bfloat16* out_wb = gate_wb + DIMC*DIMC;

    // bf16 scan outputs live in the (later overwritten) y region of d_out
    __hip_bfloat16* ylr = (__hip_bfloat16*)yfinal;                 // NROWS*STATE bf16
    __hip_bfloat16* yrl = ylr + (size_t)NROWS*STATE;               // NROWS*STATE bf16

    a_kernel<<<dim3(STATE), dim3(STATE), 0, stream>>>(U, V, Atb16);
    prep_weights<<<dim3(256, 4), dim3(256), 0, stream>>>(in_w, B_w, gate_w, out_w,
                                                         in_wb, B_wb, gate_wb, out_wb);
    gemm_inB<<<dim3(NROWS/64), dim3(512), 0, stream>>>(x, in_wb, in_b, B_wb, B_b, state_out, bxb);
    scan_mfma<<<dim3(128), dim3(256), 0, stream>>>(bxb, Atb16, ylr, yrl);
    conv_combine<<<dim3(LSEQ/8, NBATCH), dim3(128), 0, stream>>>(ylr, yrl, conv_w, conv_b, ub);
    fused_out<<<dim3(NROWS/64), dim3(512), 0, stream>>>(x, ub, out_wb, out_b, gate_wb, gate_b,
                                                        norm_g, norm_b, yfinal);
    (void)in_sizes; (void)n_in; (void)out_size; (void)ws_size;
}

// Round 13
// 149.771 us; speedup vs baseline: 1.1376x; 1.1201x over previous
//
#include <hip/hip_runtime.h>
#include <hip/hip_bf16.h>

#define DIMC 256
#define STATE 128
#define RANK 64
#define NBATCH 16
#define LSEQ 4096
#define NROWS (NBATCH*LSEQ)   // 65536
#define LN_EPS 1e-5f
#define XSTR 264              // LDS row stride (bf16 elems) for staged x tiles
#define X1STR 136             // LDS row stride for x1 transpose tile

typedef __attribute__((ext_vector_type(8))) short frag8;   // 8 bf16 (4 VGPRs)
typedef __attribute__((ext_vector_type(4))) float f32x4;   // 4 fp32

union Pack4 { __hip_bfloat16 h[4]; uint2 u; };
union Pack8 { __hip_bfloat16 h[8]; uint4 u; };

__device__ inline void gload_lds16(const void* g, void* l) {
    __builtin_amdgcn_global_load_lds((const __attribute__((address_space(1))) void*)g,
                                     (__attribute__((address_space(3))) void*)l, 16, 0, 0);
}

// Stage a [NROWSW][32-k] bf16 weight slice into LDS linear [row][64B] via global_load_lds.
// Global source pre-swizzled (col ^= (row>>1)&3) so b128 frag reads spread banks.
template<int NROWSW, int NTHR>
__device__ inline void stage_wslice(const __hip_bfloat16* __restrict__ W, int Krow, int k0,
                                    __hip_bfloat16* dst, int t) {
    constexpr int ROUNDS = (NROWSW*64) / (NTHR*16);
    const int lane = t & 63, w = t >> 6;
    #pragma unroll
    for (int j = 0; j < ROUNDS; ++j) {
        int base = (w*ROUNDS + j) << 10;       // wave-uniform byte base in slice
        int X = base + lane*16;
        int r = X >> 6;
        int cg = (X >> 4) & 3;
        const __hip_bfloat16* src = W + (size_t)r*Krow + k0 + ((cg ^ ((r>>1)&3)) << 3);
        gload_lds16(src, (char*)dst + base);
    }
}
__device__ inline frag8 ld_wfrag(const __hip_bfloat16* buf, int row, int q) {
    return *(const frag8*)((const char*)buf + (row<<6) + ((q ^ ((row>>1)&3))<<4));
}

// ---------------- At[j][i] = A[i][j] = sum_r V[i,r]*U[j,r], stored bf16 ----------------
__global__ __launch_bounds__(128) void a_kernel(const float* __restrict__ U, const float* __restrict__ V,
                                                __hip_bfloat16* __restrict__ At) {
    int i = blockIdx.x, j = threadIdx.x;
    float s = 0.f;
    #pragma unroll
    for (int r = 0; r < RANK; ++r) s += V[i*RANK + r] * U[j*RANK + r];
    At[j*STATE + i] = __float2bfloat16(s);
}

// ---------------- weights fp32 -> bf16 ----------------
__global__ __launch_bounds__(256) void prep_weights(const float* __restrict__ in_w, const float* __restrict__ B_w,
                                                    const float* __restrict__ gate_w, const float* __restrict__ out_w,
                                                    __hip_bfloat16* __restrict__ in_wb, __hip_bfloat16* __restrict__ B_wb,
                                                    __hip_bfloat16* __restrict__ gate_wb, __hip_bfloat16* __restrict__ out_wb) {
    int idx = blockIdx.x*256 + threadIdx.x;
    int which = blockIdx.y;
    if (which == 0) { if (idx < STATE*DIMC)  in_wb[idx]   = __float2bfloat16(in_w[idx]); }
    else if (which == 1) { if (idx < STATE*STATE) B_wb[idx] = __float2bfloat16(B_w[idx]); }
    else if (which == 2) { if (idx < DIMC*DIMC)  gate_wb[idx] = __float2bfloat16(gate_w[idx]); }
    else { if (idx < DIMC*STATE) out_wb[idx] = __float2bfloat16(out_w[idx]); }
}

// ---- stage x[b][0..255][l0..l0+64) into LDS bf16 [l][cin^((l&3)<<3)], stride XSTR ----
// 1024 units of (4ch x 4l); per unit: 4x float4 coalesced loads -> in-reg transpose -> 4x ds_write_b64
template<int NTHR>
__device__ inline void stage_x64(const float* __restrict__ xb, int l0,
                                 __hip_bfloat16* __restrict__ xs, int t) {
    constexpr int UN = 1024 / NTHR;
    #pragma unroll
    for (int uu = 0; uu < UN; ++uu) {
        int unit = t + uu*NTHR;
        int lg = unit & 15, cg = unit >> 4;    // cg 0..63, lg 0..15
        int l = lg*4;
        float4 v0 = *(const float4*)(xb + (size_t)(cg*4+0)*LSEQ + l0 + l);
        float4 v1 = *(const float4*)(xb + (size_t)(cg*4+1)*LSEQ + l0 + l);
        float4 v2 = *(const float4*)(xb + (size_t)(cg*4+2)*LSEQ + l0 + l);
        float4 v3 = *(const float4*)(xb + (size_t)(cg*4+3)*LSEQ + l0 + l);
        const float* p0 = (const float*)&v0; const float* p1 = (const float*)&v1;
        const float* p2 = (const float*)&v2; const float* p3 = (const float*)&v3;
        #pragma unroll
        for (int li = 0; li < 4; ++li) {
            Pack4 p;
            p.h[0] = __float2bfloat16(p0[li]);
            p.h[1] = __float2bfloat16(p1[li]);
            p.h[2] = __float2bfloat16(p2[li]);
            p.h[3] = __float2bfloat16(p3[li]);
            int row = l + li;
            int col = (cg*4) ^ ((row&3)<<3);
            *(uint2*)(xs + (size_t)row*XSTR + col) = p.u;
        }
    }
}
__device__ inline frag8 ld_xfrag(const __hip_bfloat16* __restrict__ xs, int row, int k) {
    return *(const frag8*)(xs + (size_t)row*XSTR + (k ^ ((row&3)<<3)));
}

// ---------------- fused in_proj + B GEMM with LDS-staged dbuf weights ----------------
// block = 64 l rows, 512 threads = 8 waves in 4(M) x 2(N).
__global__ __launch_bounds__(512) void gemm_inB(const float* __restrict__ x,
                                                const __hip_bfloat16* __restrict__ in_wb, const float* __restrict__ in_b,
                                                const __hip_bfloat16* __restrict__ B_wb, const float* __restrict__ B_b,
                                                float* __restrict__ state_out, float* __restrict__ bx) {
    __shared__ __hip_bfloat16 xs[64*XSTR];                  // 33792 B; x1s aliases after GEMM1
    __shared__ __hip_bfloat16 wsl[2][4096];                 // 2 x 8192 B weight slices
    __hip_bfloat16* x1s = xs;
    const int t = threadIdx.x;
    const int lane = t & 63;
    const int c = lane & 15, q = lane >> 4;
    const int w = t >> 6, wm = w >> 1, wc = w & 1;
    const int r0 = blockIdx.x * 64;
    const int b = r0 >> 12, l0 = r0 & 4095;

    stage_x64<512>(x + (size_t)b*DIMC*LSEQ, l0, xs, t);
    stage_wslice<STATE,512>(in_wb, DIMC, 0, wsl[0], t);
    __syncthreads();

    // GEMM 1: x1[l][s] = sum_c x*W_in  (8 k-slices, dbuf)
    f32x4 acc[4] = {};
    #pragma unroll
    for (int i = 0; i < 8; ++i) {
        if (i < 7) stage_wslice<STATE,512>(in_wb, DIMC, (i+1)*32, wsl[(i+1)&1], t);
        frag8 af = ld_xfrag(xs, wm*16 + c, i*32 + q*8);
        #pragma unroll
        for (int nt = 0; nt < 4; ++nt) {
            frag8 bf = ld_wfrag(wsl[i&1], wc*64 + nt*16 + c, q);
            acc[nt] = __builtin_amdgcn_mfma_f32_16x16x32_bf16(af, bf, acc[nt], 0, 0, 0);
        }
        __syncthreads();
    }

    stage_wslice<STATE,512>(B_wb, STATE, 0, wsl[0], t);   // prologue for GEMM2

    // emit x1: fp32 -> state_out, bf16 -> swizzled LDS transpose
    #pragma unroll
    for (int nt = 0; nt < 4; ++nt) {
        int col = wc*64 + nt*16 + c;
        float bb = in_b[col];
        #pragma unroll
        for (int r = 0; r < 4; ++r) {
            int row = wm*16 + q*4 + r;
            float v = acc[nt][r] + bb;
            state_out[(size_t)(r0 + row)*STATE + col] = v;
            x1s[(size_t)row*X1STR + (col ^ ((row&3)<<3))] = __float2bfloat16(v);
        }
    }
    __syncthreads();

    // GEMM 2: bx[l][s'] = sum_s x1*B_w  (4 k-slices, dbuf)
    f32x4 acc2[4] = {};
    #pragma unroll
    for (int i = 0; i < 4; ++i) {
        if (i < 3) stage_wslice<STATE,512>(B_wb, STATE, (i+1)*32, wsl[(i+1)&1], t);
        int row = wm*16 + c;
        frag8 af = *(const frag8*)(x1s + (size_t)row*X1STR + (((i*32) + q*8) ^ ((row&3)<<3)));
        #pragma unroll
        for (int nt = 0; nt < 4; ++nt) {
            frag8 bf = ld_wfrag(wsl[i&1], wc*64 + nt*16 + c, q);
            acc2[nt] = __builtin_amdgcn_mfma_f32_16x16x32_bf16(af, bf, acc2[nt], 0, 0, 0);
        }
        __syncthreads();
    }
    const int orow = r0 + wm*16 + q*4;
    #pragma unroll
    for (int nt = 0; nt < 4; ++nt) {
        int col = wc*64 + nt*16 + c;
        float bb = B_b[col];
        #pragma unroll
        for (int r = 0; r < 4; ++r)
            bx[(size_t)(orow + r)*STATE + col] = acc2[nt][r] + bb;
    }
}

// ---------------- MFMA batched scan: 16 scans/block, 4 waves (32 state rows each) ----------------
#define HSTRIDE 144
__global__ __launch_bounds__(256, 1) void scan_mfma(const float* __restrict__ bx,
                                                    const __hip_bfloat16* __restrict__ At,
                                                    __hip_bfloat16* __restrict__ ylr,
                                                    __hip_bfloat16* __restrict__ yrl) {
    __shared__ __hip_bfloat16 Hb[16 * HSTRIDE];
    const int t = threadIdx.x;
    const int l = t & 63;
    const int wm = t >> 6;
    const int c = l & 15;
    const int q = l >> 4;

    const int S   = blockIdx.x * 16 + c;
    const int dir = S >> 10;
    const int b   = (S >> 6) & 15;
    const int blk = S & 63;
    const int lp0 = blk * 64;
    const int lorig0 = dir ? (LSEQ - 1 - lp0) : lp0;
    const int sgnstep = dir ? -STATE : STATE;

    const float* bxrow = bx + ((size_t)b*LSEQ + lorig0)*STATE;
    __hip_bfloat16* yrow = (dir ? yrl : ylr) + ((size_t)b*LSEQ + lp0)*STATE;

    frag8 afr[2][4];
    #pragma unroll
    for (int mm = 0; mm < 2; ++mm)
        #pragma unroll
        for (int kc = 0; kc < 4; ++kc)
            afr[mm][kc] = *(const frag8*)(At + (size_t)((wm*2+mm)*16 + c)*STATE + kc*32 + q*8);

    for (int k = t; k < 16*HSTRIDE; k += 256) Hb[k] = __float2bfloat16(0.f);
    __syncthreads();

    f32x4 pf[2];
    #pragma unroll
    for (int mm = 0; mm < 2; ++mm)
        pf[mm] = *(const f32x4*)(bxrow + (wm*2+mm)*16 + q*4);

    for (int tt = 0; tt < 64; ++tt) {
        frag8 bfr[4];
        #pragma unroll
        for (int kc = 0; kc < 4; ++kc)
            bfr[kc] = *(const frag8*)(&Hb[c*HSTRIDE + kc*32 + q*8]);

        f32x4 acc[2];
        #pragma unroll
        for (int mm = 0; mm < 2; ++mm) {
            f32x4 a = {0.f, 0.f, 0.f, 0.f};
            #pragma unroll
            for (int kc = 0; kc < 4; ++kc)
                a = __builtin_amdgcn_mfma_f32_16x16x32_bf16(afr[mm][kc], bfr[kc], a, 0, 0, 0);
            acc[mm] = a + pf[mm];
        }
        if (tt < 63) {
            bxrow += sgnstep;
            #pragma unroll
            for (int mm = 0; mm < 2; ++mm)
                pf[mm] = *(const f32x4*)(bxrow + (wm*2+mm)*16 + q*4);
        }

        Pack4 pk[2];
        #pragma unroll
        for (int mm = 0; mm < 2; ++mm) {
            pk[mm].h[0] = __float2bfloat16(acc[mm][0]);
            pk[mm].h[1] = __float2bfloat16(acc[mm][1]);
            pk[mm].h[2] = __float2bfloat16(acc[mm][2]);
            pk[mm].h[3] = __float2bfloat16(acc[mm][3]);
        }
        #pragma unroll
        for (int mm = 0; mm < 2; ++mm)
            *(uint2*)(yrow + (wm*2+mm)*16 + q*4) = pk[mm].u;
        yrow += STATE;

        __syncthreads();
        #pragma unroll
        for (int mm = 0; mm < 2; ++mm)
            *(uint2*)(&Hb[c*HSTRIDE + (wm*2+mm)*16 + q*4]) = pk[mm].u;
        __syncthreads();
    }
}

// ---------------- conv7 + combine: u = 0.5*(conv(ylr)+rev(conv(yrl))) + conv_b, bf16 io ----------------
__global__ __launch_bounds__(128) void conv_combine(const __hip_bfloat16* __restrict__ ylr,
                                                    const __hip_bfloat16* __restrict__ yrl,
                                                    const float* __restrict__ conv_w, const float* __restrict__ conv_b,
                                                    __hip_bfloat16* __restrict__ u) {
    const int t = threadIdx.x;
    const int s8 = (t & 15) * 8;
    const int l = blockIdx.x * 8 + (t >> 4);
    const int b = blockIdx.y;

    float wv[8][7];
    #pragma unroll
    for (int j = 0; j < 8; ++j)
        #pragma unroll
        for (int i = 0; i < 7; ++i) wv[j][i] = conv_w[(s8+j)*7 + i];

    const __hip_bfloat16* plr = ylr + (size_t)b*LSEQ*STATE;
    const __hip_bfloat16* prl = yrl + (size_t)b*LSEQ*STATE;

    float acc[8];
    {
        Pack8 v; v.u = *(const uint4*)(plr + (size_t)l*STATE + s8);
        #pragma unroll
        for (int j = 0; j < 8; ++j) acc[j] = __bfloat162float(v.h[j]);
    }
    #pragma unroll
    for (int i = 0; i < 7; ++i) {
        int qq = l - 3 + i;
        if (qq >= 0 && qq < LSEQ) {
            Pack8 v; v.u = *(const uint4*)(plr + (size_t)qq*STATE + s8);
            #pragma unroll
            for (int j = 0; j < 8; ++j) acc[j] += wv[j][i] * __bfloat162float(v.h[j]);
        }
    }
    const int lp = LSEQ - 1 - l;
    {
        Pack8 v; v.u = *(const uint4*)(prl + (size_t)lp*STATE + s8);
        #pragma unroll
        for (int j = 0; j < 8; ++j) acc[j] += __bfloat162float(v.h[j]);
    }
    #pragma unroll
    for (int i = 0; i < 7; ++i) {
        int qq = lp - 3 + i;
        if (qq >= 0 && qq < LSEQ) {
            Pack8 v; v.u = *(const uint4*)(prl + (size_t)qq*STATE + s8);
            #pragma unroll
            for (int j = 0; j < 8; ++j) acc[j] += wv[j][i] * __bfloat162float(v.h[j]);
        }
    }
    Pack8 o;
    #pragma unroll
    for (int j = 0; j < 8; ++j) o.h[j] = __float2bfloat16(0.5f*acc[j] + conv_b[s8+j]);
    *(uint4*)(u + ((size_t)b*LSEQ + l)*STATE + s8) = o.u;
}

// ---------------- fused MFMA: gate+out GEMM (LDS-staged dbuf weights) + epilogue ----------------
// block = 64 l x 256 c; 512 threads = 8 waves in 4(M) x 2(N).
__global__ __launch_bounds__(512) void fused_out(const float* __restrict__ x, const __hip_bfloat16* __restrict__ ub,
    const __hip_bfloat16* __restrict__ out_wb, const float* __restrict__ out_b,
    const __hip_bfloat16* __restrict__ gate_wb, const float* __restrict__ gate_b,
    const float* __restrict__ norm_g, const float* __restrict__ norm_b,
    float* __restrict__ y) {
    __shared__ __hip_bfloat16 xs[64*XSTR];         // 33792 B
    __shared__ __hip_bfloat16 wsl[2][8192];        // 2 x 16384 B weight slices (256 rows)
    __shared__ float lnbuf[4][2][16][2];
    const int t = threadIdx.x;
    const int lane = t & 63, c = lane & 15, q = lane >> 4;
    const int w = t >> 6, wm = w >> 1, wc = w & 1;
    const int r0 = blockIdx.x * 64;
    const int b = r0 >> 12, l0 = r0 & 4095;

    stage_x64<512>(x + (size_t)b*DIMC*LSEQ, l0, xs, t);
    // u A-frags prefetched to registers (latency hidden under gate GEMM)
    frag8 ufr[4];
    {
        const int arow = r0 + wm*16 + c;
        #pragma unroll
        for (int kc = 0; kc < 4; ++kc)
            ufr[kc] = *(const frag8*)(ub + (size_t)arow*STATE + kc*32 + q*8);
    }
    stage_wslice<DIMC,512>(gate_wb, DIMC, 0, wsl[0], t);
    __syncthreads();

    f32x4 accg[8] = {};
    f32x4 acco[8] = {};
    #pragma unroll
    for (int i = 0; i < 12; ++i) {
        if (i < 11) {
            if (i < 7) stage_wslice<DIMC,512>(gate_wb, DIMC, (i+1)*32, wsl[(i+1)&1], t);
            else       stage_wslice<DIMC,512>(out_wb,  STATE, (i-7)*32, wsl[(i+1)&1], t);
        }
        if (i < 8) {
            frag8 af = ld_xfrag(xs, wm*16 + c, i*32 + q*8);
            #pragma unroll
            for (int nt = 0; nt < 8; ++nt) {
                frag8 bf = ld_wfrag(wsl[i&1], wc*128 + nt*16 + c, q);
                accg[nt] = __builtin_amdgcn_mfma_f32_16x16x32_bf16(af, bf, accg[nt], 0, 0, 0);
            }
        } else {
            frag8 af = ufr[i-8];
            #pragma unroll
            for (int nt = 0; nt < 8; ++nt) {
                frag8 bf = ld_wfrag(wsl[i&1], wc*128 + nt*16 + c, q);
                acco[nt] = __builtin_amdgcn_mfma_f32_16x16x32_bf16(af, bf, acco[nt], 0, 0, 0);
            }
        }
        __syncthreads();
    }

    // epilogue in registers: v = sigmoid(gate)*o + residual(from xs); LN partials
    float s1[4] = {0.f,0.f,0.f,0.f}, s2[4] = {0.f,0.f,0.f,0.f};
    #pragma unroll
    for (int nt = 0; nt < 8; ++nt) {
        int col = wc*128 + nt*16 + c;
        float gb = gate_b[col], ob = out_b[col];
        #pragma unroll
        for (int r = 0; r < 4; ++r) {
            int row = wm*16 + q*4 + r;
            float res = __bfloat162float(xs[(size_t)row*XSTR + (col ^ ((row&3)<<3))]);
            float g = 1.f/(1.f + expf(-(accg[nt][r] + gb)));
            float v = g*(acco[nt][r] + ob) + res;
            accg[nt][r] = v;
            s1[r] += v; s2[r] += v*v;
        }
    }
    #pragma unroll
    for (int m = 1; m <= 8; m <<= 1) {
        #pragma unroll
        for (int r = 0; r < 4; ++r) {
            s1[r] += __shfl_xor(s1[r], m);
            s2[r] += __shfl_xor(s2[r], m);
        }
    }
    if (c == 0) {
        #pragma unroll
        for (int r = 0; r < 4; ++r) {
            lnbuf[wm][wc][q*4 + r][0] = s1[r];
            lnbuf[wm][wc][q*4 + r][1] = s2[r];
        }
    }
    __syncthreads();
    float mu[4], rstd[4];
    #pragma unroll
    for (int r = 0; r < 4; ++r) {
        int row16 = q*4 + r;
        float t1 = lnbuf[wm][0][row16][0] + lnbuf[wm][1][row16][0];
        float t2 = lnbuf[wm][0][row16][1] + lnbuf[wm][1][row16][1];
        float m_ = t1 * (1.f/256.f);
        mu[r] = m_;
        rstd[r] = rsqrtf(t2 * (1.f/256.f) - m_*m_ + LN_EPS);
    }
    #pragma unroll
    for (int nt = 0; nt < 8; ++nt) {
        int col = wc*128 + nt*16 + c;
        float g = norm_g[col], be = norm_b[col];
        float4 v4;
        v4.x = (accg[nt][0] - mu[0]) * rstd[0] * g + be;
        v4.y = (accg[nt][1] - mu[1]) * rstd[1] * g + be;
        v4.z = (accg[nt][2] - mu[2]) * rstd[2] * g + be;
        v4.w = (accg[nt][3] - mu[3]) * rstd[3] * g + be;
        *(float4*)(y + ((size_t)b*DIMC + col)*LSEQ + l0 + wm*16 + q*4) = v4;
    }
}

extern "C" void kernel_launch(void* const* d_in, const int* in_sizes, int n_in,
                              void* d_out, int out_size, void* d_ws, size_t ws_size,
                              hipStream_t stream) {
    const float* x      = (const float*)d_in[0];
    const float* in_w   = (const float*)d_in[1];
    const float* in_b   = (const float*)d_in[2];
    const float* U      = (const float*)d_in[3];
    const float* V      = (const float*)d_in[4];
    const float* B_w    = (const float*)d_in[5];
    const float* B_b    = (const float*)d_in[6];
    const float* out_w  = (const float*)d_in[7];
    const float* out_b  = (const float*)d_in[8];
    const float* gate_w = (const float*)d_in[9];
    const float* gate_b = (const float*)d_in[10];
    const float* norm_g = (const float*)d_in[11];
    const float* norm_b = (const float*)d_in[12];
    const float* conv_w = (const float*)d_in[13];
    const float* conv_b = (const float*)d_in[14];

    float* yfinal = (float*)d_out;                                 // [16][256][64][64]
    float* state_out = yfinal + (size_t)NBATCH*DIMC*LSEQ;          // [16][4096][128] fp32

    float* ws  = (float*)d_ws;
    float* bxu = ws;                                               // bx fp32; later u bf16
    __hip_bfloat16* ub = (__hip_bfloat16*)ws;
    __hip_bfloat16* Atb16  = (__hip_bfloat16*)(ws + (size_t)NROWS*STATE);
    __hip_bfloat16* in_wb  = Atb16 + STATE*STATE;
    __hip_bfloat16* B_wb   = in_wb + STATE*DIMC;
    __hip_bfloat16* gate_wb= B_wb + STATE*STATE;
    __hip_bfloat16* out_wb = gate_wb + DIMC*DIMC;

    // bf16 scan outputs live in the (later overwritten) y region of d_out
    __hip_bfloat16* ylr = (__hip_bfloat16*)yfinal;                 // NROWS*STATE bf16
    __hip_bfloat16* yrl = ylr + (size_t)NROWS*STATE;               // NROWS*STATE bf16

    a_kernel<<<dim3(STATE), dim3(STATE), 0, stream>>>(U, V, Atb16);
    prep_weights<<<dim3(256, 4), dim3(256), 0, stream>>>(in_w, B_w, gate_w, out_w,
                                                         in_wb, B_wb, gate_wb, out_wb);
    gemm_inB<<<dim3(NROWS/64), dim3(512), 0, stream>>>(x, in_wb, in_b, B_wb, B_b, state_out, bxu);
    scan_mfma<<<dim3(128), dim3(256), 0, stream>>>(bxu, Atb16, ylr, yrl);
    conv_combine<<<dim3(LSEQ/8, NBATCH), dim3(128), 0, stream>>>(ylr, yrl, conv_w, conv_b, ub);
    fused_out<<<dim3(NROWS/64), dim3(512), 0, stream>>>(x, ub, out_wb, out_b, gate_wb, gate_b,
                                                        norm_g, norm_b, yfinal);
    (void)in_sizes; (void)n_in; (void)out_size; (void)ws_size;
}